// Round 1
// baseline (1535.208 us; speedup 1.0000x reference)
//
#include <hip/hip_runtime.h>
#include <math.h>

// B=64, S=128, E=512, H=512, A=256, V=8192, T=32
#define BB 64
#define SS 128
#define EE 512
#define HH 512
#define AA 256
#define VV 8192
#define TT 32

typedef __bf16 bf16x8 __attribute__((ext_vector_type(8)));
typedef __bf16 bf16x4 __attribute__((ext_vector_type(4)));
typedef float  f32x4  __attribute__((ext_vector_type(4)));

__device__ __forceinline__ bf16x8 cvt_v(float4 u, float4 v) {
    bf16x8 r;
    r[0] = (__bf16)u.x; r[1] = (__bf16)u.y; r[2] = (__bf16)u.z; r[3] = (__bf16)u.w;
    r[4] = (__bf16)v.x; r[5] = (__bf16)v.y; r[6] = (__bf16)v.z; r[7] = (__bf16)v.w;
    return r;
}

#define LDW(d, p) { const float4* q_ = (const float4*)(p); d##0 = q_[0]; d##1 = q_[1]; d##2 = q_[2]; d##3 = q_[3]; }

// ---------------------------------------------------------------------------
// fp32 GEMM (NN): C[M,N] = A[M,K] * B[K,N]. One-time enc_proj only.
// ---------------------------------------------------------------------------
__global__ __launch_bounds__(256) void gemm_nn(
    const float* __restrict__ A, int lda,
    const float* __restrict__ B, int ldb,
    float* __restrict__ C, int ldc, int K)
{
    __shared__ float As[16][68];
    __shared__ float Bs[16][68];
    const int tid = threadIdx.x;
    const int m0 = blockIdx.x * 64, n0 = blockIdx.y * 64;
    const int row = tid >> 2, kq = (tid & 3) * 4;
    const int kk = tid >> 4, nq = (tid & 15) * 4;
    const int tm = tid >> 4, tn = tid & 15;
    float acc[4][4] = {};
    for (int k0 = 0; k0 < K; k0 += 16) {
        float4 av = *(const float4*)(A + (size_t)(m0 + row) * lda + k0 + kq);
        float4 bv = *(const float4*)(B + (size_t)(k0 + kk) * ldb + n0 + nq);
        As[kq + 0][row] = av.x; As[kq + 1][row] = av.y;
        As[kq + 2][row] = av.z; As[kq + 3][row] = av.w;
        *(float4*)&Bs[kk][nq] = bv;
        __syncthreads();
#pragma unroll
        for (int k = 0; k < 16; ++k) {
            float4 a = *(const float4*)&As[k][tm * 4];
            float4 b = *(const float4*)&Bs[k][tn * 4];
            acc[0][0] += a.x * b.x; acc[0][1] += a.x * b.y; acc[0][2] += a.x * b.z; acc[0][3] += a.x * b.w;
            acc[1][0] += a.y * b.x; acc[1][1] += a.y * b.y; acc[1][2] += a.y * b.z; acc[1][3] += a.y * b.w;
            acc[2][0] += a.z * b.x; acc[2][1] += a.z * b.y; acc[2][2] += a.z * b.z; acc[2][3] += a.z * b.w;
            acc[3][0] += a.w * b.x; acc[3][1] += a.w * b.y; acc[3][2] += a.w * b.z; acc[3][3] += a.w * b.w;
        }
        __syncthreads();
    }
#pragma unroll
    for (int i = 0; i < 4; ++i) {
        float4 r = make_float4(acc[i][0], acc[i][1], acc[i][2], acc[i][3]);
        *(float4*)(C + (size_t)(m0 + tm * 4 + i) * ldc + n0 + tn * 4) = r;
    }
}

// ---------------------------------------------------------------------------
// One-time fp32 -> bf16 conversions (only when workspace is large enough).
// ---------------------------------------------------------------------------
__global__ __launch_bounds__(256) void k_cvt_bf16(
    const float* __restrict__ src, __bf16* __restrict__ dst, size_t n4)
{
    size_t i = (size_t)blockIdx.x * 256 + threadIdx.x;
    if (i < n4) {
        float4 v = *(const float4*)(src + i * 4);
        bf16x4 r;
        r[0] = (__bf16)v.x; r[1] = (__bf16)v.y; r[2] = (__bf16)v.z; r[3] = (__bf16)v.w;
        *(bf16x4*)(dst + i * 4) = r;
    }
}

// Build combined gates weight Wg[2048][1536] in the gates kernel's exact
// (permuted-row, K-reordered) access order: row n <-> gate row j=((n&3)<<9)+(n>>2);
// k<512 = W_hh[j], 512..1023 = W_ih[j][512..1023] (ctx), 1024..1535 = W_ih[j][0..511] (emb).
__global__ __launch_bounds__(256) void k_cvt_gates(
    const float* __restrict__ W_ih, const float* __restrict__ W_hh,
    __bf16* __restrict__ Wg)
{
    const int n = blockIdx.x;
    const int j = ((n & 3) << 9) + (n >> 2);
    for (int k = threadIdx.x * 4; k < 1536; k += 1024) {
        const float* src = (k < 512)  ? (W_hh + (size_t)j * 512 + k)
                         : (k < 1024) ? (W_ih + (size_t)j * 1024 + k)
                                      : (W_ih + (size_t)j * 1024 + (k - 1024));
        float4 v = *(const float4*)src;
        bf16x4 r;
        r[0] = (__bf16)v.x; r[1] = (__bf16)v.y; r[2] = (__bf16)v.z; r[3] = (__bf16)v.w;
        *(bf16x4*)(Wg + (size_t)n * 1536 + k) = r;
    }
}

// ---------------------------------------------------------------------------
// FUSED kernel: logits GEMM for step t-1 (blocks [0,nOut)) runs concurrently
// with the attention step t (blocks [nOut, nOut+64)). The two are mutually
// independent given gates(t-1): out reads h_new(t-1)+xh_ce(t-1); attn reads
// fp32 hbuf(t-1) and writes xh_ce(t) (double-buffered).
// 1024 threads/block. out blocks: 4 groups x 256 thr, each a 64-wide N-tile.
// ---------------------------------------------------------------------------
template<bool BF16W>
__global__ __launch_bounds__(1024) void fused_out_attn(
    // ---- logits part (step tprev)
    const __bf16* __restrict__ hA,     // [64][512]  h_new(t-1) bf16
    const __bf16* __restrict__ xA,     // [64][1024] xh_ce(t-1), ctx first 512
    const float*  __restrict__ Wo_f,   // [8192][1024] fp32 (fallback)
    const __bf16* __restrict__ Wo_b,   // [8192][1024] bf16 (big-ws path)
    const float*  __restrict__ b_out,
    float* __restrict__ out, int tprev,
    // ---- attention part (step t)
    const float* __restrict__ encf,    // [64,128,512]
    const float* __restrict__ encp,    // [64,128,256]
    const float* __restrict__ W_dec,   // [512,256]
    const float* __restrict__ b_att,   // [256]
    const float* __restrict__ v_att,   // [256]
    const float* __restrict__ emb,     // [8192,512]
    const int*   __restrict__ tgt,     // [64,32]
    const float* __restrict__ h,       // [64,512] fp32
    __bf16* __restrict__ xh_cur,       // [64,1024] xh_ce(t)
    int t, int nOut)
{
    // union'd LDS: out path needs 4 groups x Bs[2][64][72] bf16 = 73728 B;
    // attn path carves 13312 B of floats from the same buffer.
    __shared__ __align__(16) char smem[73728];
    const int tid = threadIdx.x;

    if ((int)blockIdx.x < nOut) {
        // ================= logits GEMM (step tprev) =================
        const int g = tid >> 8, gtid = tid & 255;
        __bf16 (*Bs)[64][72] = (__bf16 (*)[64][72])(smem + (size_t)g * 18432);
        const int n0 = (int)blockIdx.x * 256 + g * 64;
        const int wv = gtid >> 6, lane = gtid & 63;
        const int quad = lane >> 4, l16 = lane & 15;
        const int row = gtid >> 2, cq = gtid & 3;
        const __bf16* aHp = hA + (size_t)(wv * 16 + l16) * 512 + quad * 8;
        const __bf16* aXp = xA + (size_t)(wv * 16 + l16) * 1024 + quad * 8;

        f32x4 acc[4] = {{0,0,0,0},{0,0,0,0},{0,0,0,0},{0,0,0,0}};
        bf16x8 aC0 = *(const bf16x8*)aHp, aC1 = *(const bf16x8*)(aHp + 32);
        bf16x8 aN0, aN1;

        float4 wA0, wA1, wA2, wA3, wB0, wB1, wB2, wB3;
        bf16x8 pA0, pA1, pB0, pB1;
        const float*  bsf = nullptr;
        const __bf16* bsb = nullptr;
        if constexpr (BF16W) {
            bsb = Wo_b + (size_t)(n0 + row) * 1024 + cq * 16;
            const bf16x8* q0 = (const bf16x8*)bsb;        pA0 = q0[0]; pA1 = q0[1];
            const bf16x8* q1 = (const bf16x8*)(bsb + 64); pB0 = q1[0]; pB1 = q1[1];
        } else {
            bsf = Wo_f + (size_t)(n0 + row) * 1024 + cq * 16;
            LDW(wA, bsf); LDW(wB, bsf + 64);
        }

        for (int it = 0; it < 16; ++it) {
            __bf16* dst = &Bs[it & 1][row][cq * 16];
            if constexpr (BF16W) {
                *(bf16x8*)dst       = pA0;
                *(bf16x8*)(dst + 8) = pA1;
            } else {
                *(bf16x8*)dst       = cvt_v(wA0, wA1);
                *(bf16x8*)(dst + 8) = cvt_v(wA2, wA3);
            }
            __syncthreads();
            if constexpr (BF16W) {
                pA0 = pB0; pA1 = pB1;
                if (it + 2 < 16) {
                    const bf16x8* q = (const bf16x8*)(bsb + (it + 2) * 64);
                    pB0 = q[0]; pB1 = q[1];
                }
            } else {
                wA0 = wB0; wA1 = wB1; wA2 = wB2; wA3 = wB3;
                if (it + 2 < 16) LDW(wB, bsf + (it + 2) * 64);
            }
            if (it + 1 < 16) {
                const int itn = it + 1;
                const __bf16* ap = (itn < 8) ? (aHp + itn * 64) : (aXp + (itn - 8) * 64);
                aN0 = *(const bf16x8*)ap; aN1 = *(const bf16x8*)(ap + 32);
            }
#pragma unroll
            for (int c = 0; c < 4; ++c) {
                bf16x8 b0 = *(const bf16x8*)&Bs[it & 1][c * 16 + l16][quad * 8];
                bf16x8 b1 = *(const bf16x8*)&Bs[it & 1][c * 16 + l16][quad * 8 + 32];
                acc[c] = __builtin_amdgcn_mfma_f32_16x16x32_bf16(aC0, b0, acc[c], 0, 0, 0);
                acc[c] = __builtin_amdgcn_mfma_f32_16x16x32_bf16(aC1, b1, acc[c], 0, 0, 0);
            }
            aC0 = aN0; aC1 = aN1;
        }

        const int m = wv * 16 + quad * 4;
        const int nb = n0 + l16;
        float* op = out + (size_t)tprev * VV + nb;
#pragma unroll
        for (int r = 0; r < 4; ++r) {
            float* orow = op + (size_t)(m + r) * (TT * VV);
            orow[ 0] = acc[0][r] + b_out[nb +  0];
            orow[16] = acc[1][r] + b_out[nb + 16];
            orow[32] = acc[2][r] + b_out[nb + 32];
            orow[48] = acc[3][r] + b_out[nb + 48];
        }
    } else {
        // ================= attention (step t) =================
        const int b = (int)blockIdx.x - nOut;
        float* sh    = (float*)smem;       // 512
        float* sdec  = sh + 512;           // 256
        float* sv    = sdec + 256;         // 256
        float* sw    = sv + 256;           // 128
        float* st    = sw + 128;           // 128
        float* part  = st + 128;           // 4 x 256
        float* cpart = part + 1024;        // 2 x 512

        if (tid < 512) sh[tid] = h[(size_t)b * 512 + tid];
        else if (tid < 768) sv[tid - 512] = v_att[tid - 512];
        __syncthreads();

        // Phase 1: dec[a] = sum_k h[k] W_dec[k,a]  (split-K 4)
        {
            const int a = tid & 255, kq = tid >> 8;
            const float* w = W_dec + (size_t)kq * 128 * 256 + a;
            const float* hp = sh + kq * 128;
            float s = 0.f;
#pragma unroll 8
            for (int k = 0; k < 128; ++k) s += hp[k] * w[(size_t)k * 256];
            part[kq * 256 + a] = s;
        }
        __syncthreads();
        if (tid < 256)
            sdec[tid] = part[tid] + part[256 + tid] + part[512 + tid] + part[768 + tid] + b_att[tid];
        __syncthreads();

        // Phase 2: scores (16 waves x 8 s)
        {
            const int wv2 = tid >> 6, lane = tid & 63;
#pragma unroll
            for (int i = 0; i < 8; ++i) {
                const int s = wv2 * 8 + i;
                const float* ep = encp + ((size_t)b * 128 + s) * 256;
                float sum = 0.f;
#pragma unroll
                for (int c = 0; c < 4; ++c) {
                    int a = lane + 64 * c;
                    sum += tanhf(ep[a] + sdec[a]) * sv[a];
                }
#pragma unroll
                for (int off = 32; off > 0; off >>= 1) sum += __shfl_down(sum, off);
                if (lane == 0) sw[s] = sum;
            }
        }
        __syncthreads();

        // Phase 3: softmax (unnormalized exp in sw, sum in st[0])
        if (tid < 128) st[tid] = sw[tid];
        __syncthreads();
        for (int off = 64; off > 0; off >>= 1) {
            if (tid < off) st[tid] = fmaxf(st[tid], st[tid + off]);
            __syncthreads();
        }
        const float mx = st[0];
        __syncthreads();
        if (tid < 128) { float ex = expf(sw[tid] - mx); sw[tid] = ex; st[tid] = ex; }
        __syncthreads();
        for (int off = 64; off > 0; off >>= 1) {
            if (tid < off) st[tid] += st[tid + off];
            __syncthreads();
        }

        // Phase 4: ctx (split-S 2)
        {
            const int e = tid & 511, half = tid >> 9;
            const float* ef = encf + (size_t)b * (SS * EE) + (size_t)half * 64 * 512 + e;
            const float* wp = sw + half * 64;
            float cv = 0.f;
#pragma unroll 8
            for (int s = 0; s < 64; ++s) cv += wp[s] * ef[(size_t)s * 512];
            cpart[half * 512 + e] = cv;
        }
        __syncthreads();
        const float inv = 1.f / st[0];
        if (tid < 512) {
            xh_cur[(size_t)b * 1024 + tid] = (__bf16)((cpart[tid] + cpart[512 + tid]) * inv);
        } else {
            const int e = tid - 512;
            const int tok = (t == 0) ? 0 : tgt[b * TT + t - 1];
            xh_cur[(size_t)b * 1024 + 512 + e] = (__bf16)emb[(size_t)tok * 512 + e];
        }
    }
}

// ---------------------------------------------------------------------------
// Gates GEMM (bf16 MFMA, pipelined BK=64) + fused LSTM pointwise.
// BF16W path reads the pre-permuted combined weight Wg[2048][1536] directly.
// ---------------------------------------------------------------------------
template<bool BF16W>
__global__ __launch_bounds__(256) void gemm_gates_lstm(
    const __bf16* __restrict__ h_old,   // [64][512]
    const __bf16* __restrict__ xh_ce,   // [64][1024] = [ctx|emb]
    const float* __restrict__ W_ih,     // [2048][1024]
    const float* __restrict__ W_hh,     // [2048][512]
    const __bf16* __restrict__ Wg,      // [2048][1536] pre-permuted bf16
    const float* __restrict__ b_ih, const float* __restrict__ b_hh,
    float* __restrict__ hbuf, float* __restrict__ cbuf,
    __bf16* __restrict__ h_new)
{
    __shared__ __bf16 Bs[2][64][72];
    __shared__ float  Cf[64][68];
    const int tid = threadIdx.x;
    const int n0 = blockIdx.x * 64;
    const int wv = tid >> 6, lane = tid & 63;
    const int quad = lane >> 4, l16 = lane & 15;
    const int row = tid >> 2, cq = tid & 3;
    const int nglob = n0 + row;

    const float*  rH = nullptr;
    const float*  rI = nullptr;
    const __bf16* rB = nullptr;
    if constexpr (BF16W) {
        rB = Wg + (size_t)nglob * 1536 + cq * 16;
    } else {
        const int j = ((nglob & 3) << 9) + (nglob >> 2);
        rH = W_hh + (size_t)j * 512;
        rI = W_ih + (size_t)j * 1024;
    }

    const __bf16* aHp = h_old + (size_t)(wv * 16 + l16) * 512 + quad * 8;
    const __bf16* aXp = xh_ce + (size_t)(wv * 16 + l16) * 1024 + quad * 8;

    f32x4 acc[4] = {{0,0,0,0},{0,0,0,0},{0,0,0,0},{0,0,0,0}};

    auto wsrc = [&](int it) -> const float* {
        const int k = it * 64 + cq * 16;
        if (k < 512)  return rH + k;
        if (k < 1024) return rI + k;
        return rI + (k - 1024);
    };
    float4 wA0, wA1, wA2, wA3, wB0, wB1, wB2, wB3;
    bf16x8 pA0, pA1, pB0, pB1;
    if constexpr (BF16W) {
        const bf16x8* q0 = (const bf16x8*)rB;        pA0 = q0[0]; pA1 = q0[1];
        const bf16x8* q1 = (const bf16x8*)(rB + 64); pB0 = q1[0]; pB1 = q1[1];
    } else {
        LDW(wA, wsrc(0)); LDW(wB, wsrc(1));
    }
    bf16x8 aC0 = *(const bf16x8*)aHp, aC1 = *(const bf16x8*)(aHp + 32);
    bf16x8 aN0, aN1;

    for (int it = 0; it < 24; ++it) {
        __bf16* dst = &Bs[it & 1][row][cq * 16];
        if constexpr (BF16W) {
            *(bf16x8*)dst       = pA0;
            *(bf16x8*)(dst + 8) = pA1;
        } else {
            *(bf16x8*)dst       = cvt_v(wA0, wA1);
            *(bf16x8*)(dst + 8) = cvt_v(wA2, wA3);
        }
        __syncthreads();
        if constexpr (BF16W) {
            pA0 = pB0; pA1 = pB1;
            if (it + 2 < 24) {
                const bf16x8* q = (const bf16x8*)(rB + (it + 2) * 64);
                pB0 = q[0]; pB1 = q[1];
            }
        } else {
            wA0 = wB0; wA1 = wB1; wA2 = wB2; wA3 = wB3;
            if (it + 2 < 24) LDW(wB, wsrc(it + 2));
        }
        if (it + 1 < 24) {
            const int itn = it + 1;
            const __bf16* ap = (itn < 8) ? (aHp + itn * 64) : (aXp + (itn - 8) * 64);
            aN0 = *(const bf16x8*)ap; aN1 = *(const bf16x8*)(ap + 32);
        }
#pragma unroll
        for (int c = 0; c < 4; ++c) {
            bf16x8 b0 = *(const bf16x8*)&Bs[it & 1][c * 16 + l16][quad * 8];
            bf16x8 b1 = *(const bf16x8*)&Bs[it & 1][c * 16 + l16][quad * 8 + 32];
            acc[c] = __builtin_amdgcn_mfma_f32_16x16x32_bf16(aC0, b0, acc[c], 0, 0, 0);
            acc[c] = __builtin_amdgcn_mfma_f32_16x16x32_bf16(aC1, b1, acc[c], 0, 0, 0);
        }
        aC0 = aN0; aC1 = aN1;
    }
    __syncthreads();
#pragma unroll
    for (int r = 0; r < 4; ++r) {
        Cf[wv * 16 + quad * 4 + r][ 0 + l16] = acc[0][r];
        Cf[wv * 16 + quad * 4 + r][16 + l16] = acc[1][r];
        Cf[wv * 16 + quad * 4 + r][32 + l16] = acc[2][r];
        Cf[wv * 16 + quad * 4 + r][48 + l16] = acc[3][r];
    }
    __syncthreads();
    const int U0 = n0 >> 2;
    for (int it = tid; it < 1024; it += 256) {
        const int bb = it >> 4, ul = it & 15;
        const int ug = U0 + ul;
        const float gi = Cf[bb][4 * ul + 0] + b_ih[ug]         + b_hh[ug];
        const float gf = Cf[bb][4 * ul + 1] + b_ih[512 + ug]   + b_hh[512 + ug];
        const float gg = Cf[bb][4 * ul + 2] + b_ih[1024 + ug]  + b_hh[1024 + ug];
        const float go = Cf[bb][4 * ul + 3] + b_ih[1536 + ug]  + b_hh[1536 + ug];
        const float si = 1.f / (1.f + expf(-gi));
        const float sf = 1.f / (1.f + expf(-gf));
        const float so = 1.f / (1.f + expf(-go));
        const float cn = sf * cbuf[bb * 512 + ug] + si * tanhf(gg);
        const float hn = so * tanhf(cn);
        cbuf[bb * 512 + ug] = cn;
        hbuf[bb * 512 + ug] = hn;
        h_new[(size_t)bb * 512 + ug] = (__bf16)hn;
    }
}

// ---------------------------------------------------------------------------
__global__ void k_zero_f(float* p, int n) {
    int i = blockIdx.x * 256 + threadIdx.x;
    if (i < n) p[i] = 0.f;
}
__global__ void k_zero_bf(__bf16* p, int n) {
    int i = blockIdx.x * 256 + threadIdx.x;
    if (i < n) p[i] = (__bf16)0.f;
}

// ---------------------------------------------------------------------------
// Timestep loop. Schedule:
//   attn(0); gates(0);
//   for t=1..31: [out(t-1) || attn(t)] fused; gates(t);
//   out(31)
// ---------------------------------------------------------------------------
template<bool BIGW>
static void run_seq(
    const float* encf, const int* tgt, const float* emb,
    const float* W_dec, const float* b_att, const float* v_att,
    const float* W_ih, const float* W_hh, const float* b_ih, const float* b_hh,
    const float* W_out, const float* b_out, float* out,
    float* encp, float* hbuf, float* cbuf,
    __bf16* xh0, __bf16* xh1, __bf16* hb0, __bf16* hb1,
    const __bf16* Wg, const __bf16* Wo_b, hipStream_t stream)
{
    // t = 0: attention only (nOut = 0)
    fused_out_attn<BIGW><<<64, 1024, 0, stream>>>(
        hb0, xh0, W_out, Wo_b, b_out, out, 0,
        encf, encp, W_dec, b_att, v_att, emb, tgt, hbuf, xh0, 0, 0);
    gemm_gates_lstm<BIGW><<<32, 256, 0, stream>>>(
        hb0, xh0, W_ih, W_hh, Wg, b_ih, b_hh, hbuf, cbuf, hb1);

    for (int t = 1; t < TT; ++t) {
        __bf16* hold = (t & 1) ? hb1 : hb0;   // == h_new(t-1)
        __bf16* hnew = (t & 1) ? hb0 : hb1;
        __bf16* xhp  = ((t - 1) & 1) ? xh1 : xh0;
        __bf16* xhc  = (t & 1) ? xh1 : xh0;
        fused_out_attn<BIGW><<<96, 1024, 0, stream>>>(
            hold, xhp, W_out, Wo_b, b_out, out, t - 1,
            encf, encp, W_dec, b_att, v_att, emb, tgt, hbuf, xhc, t, 32);
        gemm_gates_lstm<BIGW><<<32, 256, 0, stream>>>(
            hold, xhc, W_ih, W_hh, Wg, b_ih, b_hh, hbuf, cbuf, hnew);
    }

    // final logits for t = 31 (nOut = 32, grid 32 -> no attn blocks)
    fused_out_attn<BIGW><<<32, 1024, 0, stream>>>(
        hb0 /* h_new(31) */, xh1 /* xh_ce(31) */, W_out, Wo_b, b_out, out, TT - 1,
        encf, encp, W_dec, b_att, v_att, emb, tgt, hbuf, xh0, 0, 32);
}

// ---------------------------------------------------------------------------
extern "C" void kernel_launch(void* const* d_in, const int* in_sizes, int n_in,
                              void* d_out, int out_size, void* d_ws, size_t ws_size,
                              hipStream_t stream)
{
    (void)in_sizes; (void)n_in; (void)out_size;
    const float* encf  = (const float*)d_in[0];
    const int*   tgt   = (const int*)  d_in[1];
    const float* emb   = (const float*)d_in[2];
    const float* W_enc = (const float*)d_in[3];
    const float* W_dec = (const float*)d_in[4];
    const float* b_att = (const float*)d_in[5];
    const float* v_att = (const float*)d_in[6];
    const float* W_ih  = (const float*)d_in[7];
    const float* W_hh  = (const float*)d_in[8];
    const float* b_ih  = (const float*)d_in[9];
    const float* b_hh  = (const float*)d_in[10];
    const float* W_out = (const float*)d_in[11];
    const float* b_out = (const float*)d_in[12];
    float* out = (float*)d_out;

    // workspace: small path ~8.6 MB (proven safe at ~9.7 MB).
    // big path adds bf16 weights (Wg 6.3 MB + Wo 16.8 MB) -> ~30.7 MB, used
    // only if ws_size allows (runtime host branch; deterministic per capture).
    float* ws = (float*)d_ws;
    size_t off = 0;
    auto alloc = [&](size_t n) { float* p = ws + off; off += (n + 255) & ~(size_t)255; return p; };
    float*  encp = alloc((size_t)BB * SS * AA);
    float*  hbuf = alloc((size_t)BB * HH);        // contiguous with cbuf for k_zero_f
    float*  cbuf = alloc((size_t)BB * HH);
    __bf16* xh0  = (__bf16*)alloc((size_t)BB * 1024 / 2);
    __bf16* xh1  = (__bf16*)alloc((size_t)BB * 1024 / 2);
    __bf16* hb0  = (__bf16*)alloc((size_t)BB * HH / 2);
    __bf16* hb1  = (__bf16*)alloc((size_t)BB * HH / 2);
    __bf16* Wg   = (__bf16*)alloc((size_t)2048 * 1536 / 2);  // only used if big
    __bf16* Wo_b = (__bf16*)alloc((size_t)VV * 1024 / 2);    // only used if big
    const bool big = off * sizeof(float) <= ws_size;

    k_zero_f<<<(2 * BB * HH + 255) / 256, 256, 0, stream>>>(hbuf, 2 * BB * HH);
    k_zero_bf<<<(BB * HH + 255) / 256, 256, 0, stream>>>(hb0, BB * HH);
    gemm_nn<<<dim3(BB * SS / 64, AA / 64), 256, 0, stream>>>(encf, EE, W_enc, AA, encp, AA, EE);

    if (big) {
        k_cvt_bf16<<<(int)(((size_t)VV * 1024 / 4 + 255) / 256), 256, 0, stream>>>(
            W_out, Wo_b, (size_t)VV * 1024 / 4);
        k_cvt_gates<<<2048, 256, 0, stream>>>(W_ih, W_hh, Wg);
        run_seq<true>(encf, tgt, emb, W_dec, b_att, v_att, W_ih, W_hh, b_ih, b_hh,
                      W_out, b_out, out, encp, hbuf, cbuf, xh0, xh1, hb0, hb1,
                      Wg, Wo_b, stream);
    } else {
        run_seq<false>(encf, tgt, emb, W_dec, b_att, v_att, W_ih, W_hh, b_ih, b_hh,
                       W_out, b_out, out, encp, hbuf, cbuf, xh0, xh1, hb0, hb1,
                       Wg, Wo_b, stream);
    }
}